// Round 2
// baseline (253.490 us; speedup 1.0000x reference)
//
#include <hip/hip_runtime.h>

// Problem constants
#define B_SZ 16
#define CIN  512
#define LIN  1024
#define LP   1022      // L - K + 1
#define HEADS 8
#define DH    64

typedef __attribute__((ext_vector_type(8))) short bf16x8;
typedef __attribute__((ext_vector_type(4))) float f32x4;

__device__ inline unsigned short f2bf(float f) {
    union { float f; unsigned int u; } c; c.f = f;
    unsigned int r = c.u + 0x7FFF + ((c.u >> 16) & 1);   // RNE
    return (unsigned short)(r >> 16);
}

// async global->LDS DMA, 16B per lane, LDS dst = wave-uniform base + lane*16
__device__ __forceinline__ void gl_lds16(const unsigned short* g, unsigned short* l) {
    __builtin_amdgcn_global_load_lds((const __attribute__((address_space(1))) void*)g,
                                     (__attribute__((address_space(3))) void*)l, 16, 0, 0);
}

// XOR swizzle on 16B granules: involution, preserves 64-granule blocks,
// spreads rows across all 8 bank groups (2-way residual = free).
#define SWZ(G) ((G) ^ (((G) >> 3) & 7))

// raw barrier + compiler memory fence (LDS ops must not cross)
#define BAR() do { asm volatile("" ::: "memory"); \
                   __builtin_amdgcn_s_barrier();  \
                   asm volatile("" ::: "memory"); } while (0)

// ---------------------------------------------------------------------------
// xb cvt: x fp32 [b][512 i][1024 l] -> xb bf16 [b][1024 l][512 i]
// ---------------------------------------------------------------------------
__global__ __launch_bounds__(256) void xb_cvt_kernel(const float* __restrict__ x,
                                                     unsigned short* __restrict__ xb) {
    __shared__ float sm[64][68];
    const int t  = threadIdx.x;
    const int l0 = blockIdx.x * 64;
    const int i0 = blockIdx.y * 64;
    const int b  = blockIdx.z;
    const float* S = x + ((size_t)b * CIN + i0) * LIN;

    #pragma unroll
    for (int rr = 0; rr < 4; rr++) {
        int idx = rr * 1024 + t * 4;
        int ii = idx >> 6, lj = idx & 63;
        *(float4*)&sm[ii][lj] = *(const float4*)(S + (size_t)ii * LIN + l0 + lj);
    }
    __syncthreads();

    #pragma unroll
    for (int rr = 0; rr < 4; rr++) {
        int idx = rr * 1024 + t * 4;
        int l = idx >> 6, dj = idx & 63;
        ushort4 h;
        h.x = f2bf(sm[dj + 0][l]);
        h.y = f2bf(sm[dj + 1][l]);
        h.z = f2bf(sm[dj + 2][l]);
        h.w = f2bf(sm[dj + 3][l]);
        *(ushort4*)(xb + ((size_t)b * 1024 + l0 + l) * 512 + i0 + dj) = h;
    }
}

// ---------------------------------------------------------------------------
// wb cvt: w_c[o][i][kk] fp32 -> wb bf16 [kk][O=c*512+o][i]
// ---------------------------------------------------------------------------
__global__ __launch_bounds__(256) void wb_cvt_kernel(const float* __restrict__ w0,
                                                     const float* __restrict__ w1,
                                                     const float* __restrict__ w2,
                                                     unsigned short* __restrict__ wb) {
    const int kk = blockIdx.y;
    int flat = blockIdx.x * 256 + threadIdx.x;
    int i  = flat & 511;
    int oG = flat >> 9;
    int c  = oG >> 9, o = oG & 511;
    const float* w = (c == 0) ? w0 : (c == 1) ? w1 : w2;
    wb[(size_t)kk * 786432 + flat] = f2bf(w[o * 1536 + i * 3 + kk]);
}

// ---------------------------------------------------------------------------
// Fused 3-conv bf16 MFMA GEMM — 8-phase counted-vmcnt structure (T3+T4+T5).
// BM=128(o) x BN=256(l) x BK=64, 24 K-tiles (kk folded into K: kt -> kk=kt>>3,
// ic=(kt&7)*64; kk shifts the B *global* row address, halo-free). 512 threads,
// 8 waves (2M x 4N, 64x64 per wave). Triple-buffered LDS (3 x 48KB = 144KB
// dynamic): stage kt+2 during kt's phases -> boundary vmcnt(6), never 0.
// 4 phases/K-tile: {stage-chunk || 4 ds_read_b128} bar setprio MFMA x8 bar,
// snake quadrant order so each frag is read once per K-tile.
// Grid 12x4x16 = 768 blocks = exactly 3 rounds of 256 CUs (100% balance).
// ---------------------------------------------------------------------------
extern __shared__ unsigned short smem[];

__device__ __forceinline__ void stage_chunkA(const unsigned short* wbase,
                                             unsigned short* bufA, int wave, int lane) {
    #pragma unroll
    for (int j = 0; j < 2; j++) {
        int i = wave * 2 + j;                    // instr 0..15 (128 rows x 8 gran)
        int G = SWZ(i * 64 + lane);
        gl_lds16(wbase + (size_t)(G >> 3) * 512 + (G & 7) * 8, bufA + i * 512);
    }
}

__device__ __forceinline__ void stage_chunkB(const unsigned short* xbase,
                                             unsigned short* bufB, int half,
                                             int wave, int lane) {
    #pragma unroll
    for (int j = 0; j < 2; j++) {
        int i = half * 16 + wave * 2 + j;        // instr 0..31 (256 rows x 8 gran)
        int G = SWZ(i * 64 + lane);
        gl_lds16(xbase + (size_t)(G >> 3) * 512 + (G & 7) * 8, bufB + i * 512);
    }
}

__device__ __forceinline__ bf16x8 ldfrag(const unsigned short* buf, int row,
                                         int ks, int quad) {
    int G = (row << 3) | (ks << 2) | quad;
    return *(const bf16x8*)&buf[SWZ(G) * 8];
}

__device__ __forceinline__ void ktile(int kt,
        const unsigned short* __restrict__ wb, const unsigned short* __restrict__ xrow,
        int o0, int l0, int wave, int lane, int col, int quad, int wr, int wc,
        unsigned short* BA, unsigned short* BB,
        unsigned short* NA, unsigned short* NB, f32x4 (&acc)[4][4]) {
    const int kn  = kt + 2;
    const int kkn = kn >> 3, icn = (kn & 7) << 6;
    const int ar = wr * 64 + col;                // A-frag row base
    const int br = wc * 64 + col;                // B-frag row base

    bf16x8 A0[2][2], A1[2][2], Bl[2][2], Bh[2][2];

    // ---- phase 0: quadrant (mh0,nh0); stage A(kt+2) ----
    if (kt < 22)
        stage_chunkA(wb + (size_t)kkn * 786432 + (size_t)o0 * 512 + icn, NA, wave, lane);
    #pragma unroll
    for (int ks = 0; ks < 2; ks++) {
        A0[0][ks] = ldfrag(BA, ar,      ks, quad);
        A0[1][ks] = ldfrag(BA, ar + 16, ks, quad);
        Bl[0][ks] = ldfrag(BB, br,      ks, quad);
        Bl[1][ks] = ldfrag(BB, br + 16, ks, quad);
    }
    BAR();
    __builtin_amdgcn_s_setprio(1);
    #pragma unroll
    for (int ks = 0; ks < 2; ks++) {
        acc[0][0] = __builtin_amdgcn_mfma_f32_16x16x32_bf16(A0[0][ks], Bl[0][ks], acc[0][0], 0, 0, 0);
        acc[0][1] = __builtin_amdgcn_mfma_f32_16x16x32_bf16(A0[0][ks], Bl[1][ks], acc[0][1], 0, 0, 0);
        acc[1][0] = __builtin_amdgcn_mfma_f32_16x16x32_bf16(A0[1][ks], Bl[0][ks], acc[1][0], 0, 0, 0);
        acc[1][1] = __builtin_amdgcn_mfma_f32_16x16x32_bf16(A0[1][ks], Bl[1][ks], acc[1][1], 0, 0, 0);
    }
    __builtin_amdgcn_s_setprio(0);
    BAR();

    // ---- phase 1: quadrant (mh0,nh1); stage B-half0(kt+2) ----
    if (kt < 22)
        stage_chunkB(xrow + (size_t)(l0 + kkn) * 512 + icn, NB, 0, wave, lane);
    #pragma unroll
    for (int ks = 0; ks < 2; ks++) {
        Bh[0][ks] = ldfrag(BB, br + 32, ks, quad);
        Bh[1][ks] = ldfrag(BB, br + 48, ks, quad);
    }
    BAR();
    __builtin_amdgcn_s_setprio(1);
    #pragma unroll
    for (int ks = 0; ks < 2; ks++) {
        acc[0][2] = __builtin_amdgcn_mfma_f32_16x16x32_bf16(A0[0][ks], Bh[0][ks], acc[0][2], 0, 0, 0);
        acc[0][3] = __builtin_amdgcn_mfma_f32_16x16x32_bf16(A0[0][ks], Bh[1][ks], acc[0][3], 0, 0, 0);
        acc[1][2] = __builtin_amdgcn_mfma_f32_16x16x32_bf16(A0[1][ks], Bh[0][ks], acc[1][2], 0, 0, 0);
        acc[1][3] = __builtin_amdgcn_mfma_f32_16x16x32_bf16(A0[1][ks], Bh[1][ks], acc[1][3], 0, 0, 0);
    }
    __builtin_amdgcn_s_setprio(0);
    BAR();

    // ---- phase 2: quadrant (mh1,nh1); stage B-half1(kt+2) ----
    if (kt < 22)
        stage_chunkB(xrow + (size_t)(l0 + kkn) * 512 + icn, NB, 1, wave, lane);
    #pragma unroll
    for (int ks = 0; ks < 2; ks++) {
        A1[0][ks] = ldfrag(BA, ar + 32, ks, quad);
        A1[1][ks] = ldfrag(BA, ar + 48, ks, quad);
    }
    BAR();
    __builtin_amdgcn_s_setprio(1);
    #pragma unroll
    for (int ks = 0; ks < 2; ks++) {
        acc[2][2] = __builtin_amdgcn_mfma_f32_16x16x32_bf16(A1[0][ks], Bh[0][ks], acc[2][2], 0, 0, 0);
        acc[2][3] = __builtin_amdgcn_mfma_f32_16x16x32_bf16(A1[0][ks], Bh[1][ks], acc[2][3], 0, 0, 0);
        acc[3][2] = __builtin_amdgcn_mfma_f32_16x16x32_bf16(A1[1][ks], Bh[0][ks], acc[3][2], 0, 0, 0);
        acc[3][3] = __builtin_amdgcn_mfma_f32_16x16x32_bf16(A1[1][ks], Bh[1][ks], acc[3][3], 0, 0, 0);
    }
    __builtin_amdgcn_s_setprio(0);
    BAR();

    // ---- phase 3: quadrant (mh1,nh0), no staging, reuse A1 + Bl ----
    __builtin_amdgcn_s_setprio(1);
    #pragma unroll
    for (int ks = 0; ks < 2; ks++) {
        acc[2][0] = __builtin_amdgcn_mfma_f32_16x16x32_bf16(A1[0][ks], Bl[0][ks], acc[2][0], 0, 0, 0);
        acc[2][1] = __builtin_amdgcn_mfma_f32_16x16x32_bf16(A1[0][ks], Bl[1][ks], acc[2][1], 0, 0, 0);
        acc[3][0] = __builtin_amdgcn_mfma_f32_16x16x32_bf16(A1[1][ks], Bl[0][ks], acc[3][0], 0, 0, 0);
        acc[3][1] = __builtin_amdgcn_mfma_f32_16x16x32_bf16(A1[1][ks], Bl[1][ks], acc[3][1], 0, 0, 0);
    }
    __builtin_amdgcn_s_setprio(0);

    // ---- tile boundary: counted vmcnt (kt+1 landed; kt+2's 6 stay in flight) ----
    if (kt < 22)       asm volatile("s_waitcnt vmcnt(6)" ::: "memory");
    else if (kt == 22) asm volatile("s_waitcnt vmcnt(0)" ::: "memory");
    BAR();
}

__global__ __launch_bounds__(512, 2) void conv_mfma_kernel(
        const unsigned short* __restrict__ xb,   // [16][1024][512]
        const unsigned short* __restrict__ wb,   // [3][1536][512]
        const float* __restrict__ b0, const float* __restrict__ b1,
        const float* __restrict__ b2,
        unsigned short* __restrict__ Qt, unsigned short* __restrict__ Kt,
        unsigned short* __restrict__ Vt, float qscale) {
    const int t    = threadIdx.x;
    const int wave = t >> 6;
    const int lane = t & 63;
    const int col  = lane & 15;
    const int quad = lane >> 4;
    const int wr   = wave >> 2;                  // 0..1 (M)
    const int wc   = wave & 3;                   // 0..3 (N)
    const int l0   = blockIdx.x * 256;
    const int o0   = blockIdx.y * 128;
    const int b    = blockIdx.z;

    // buffers: 3 x (A 8192 | B 16384) ushorts
    unsigned short* b0A = smem;          unsigned short* b0B = smem + 8192;
    unsigned short* b1A = smem + 24576;  unsigned short* b1B = smem + 32768;
    unsigned short* b2A = smem + 49152;  unsigned short* b2B = smem + 57344;

    f32x4 acc[4][4];
    #pragma unroll
    for (int i = 0; i < 4; i++)
        #pragma unroll
        for (int j = 0; j < 4; j++) acc[i][j] = (f32x4){0.f, 0.f, 0.f, 0.f};

    const unsigned short* xrow = xb + (size_t)b * 1024 * 512;

    // ---- prologue: stage kt0 -> buf0, kt1 -> buf1 (both kk=0) ----
    stage_chunkA(wb + (size_t)o0 * 512,        b0A, wave, lane);
    stage_chunkB(xrow + (size_t)l0 * 512,      b0B, 0, wave, lane);
    stage_chunkB(xrow + (size_t)l0 * 512,      b0B, 1, wave, lane);
    stage_chunkA(wb + (size_t)o0 * 512 + 64,   b1A, wave, lane);
    stage_chunkB(xrow + (size_t)l0 * 512 + 64, b1B, 0, wave, lane);
    stage_chunkB(xrow + (size_t)l0 * 512 + 64, b1B, 1, wave, lane);
    asm volatile("s_waitcnt vmcnt(6)" ::: "memory");   // kt0 landed; kt1 in flight
    BAR();

    // ---- main loop: 24 K-tiles, buffers rotate mod 3 ----
    #pragma unroll 1
    for (int ktb = 0; ktb < 24; ktb += 3) {
        ktile(ktb,     wb, xrow, o0, l0, wave, lane, col, quad, wr, wc,
              b0A, b0B, b2A, b2B, acc);
        ktile(ktb + 1, wb, xrow, o0, l0, wave, lane, col, quad, wr, wc,
              b1A, b1B, b0A, b0B, acc);
        ktile(ktb + 2, wb, xrow, o0, l0, wave, lane, col, quad, wr, wc,
              b2A, b2B, b1A, b1B, acc);
    }

    const int c = blockIdx.y >> 2;               // which conv (uniform per block)

    if (c < 2) {
        // ---- Q/K epilogue: direct bf16 stores to [bh][l][d] ----
        unsigned short* dst = (c == 0) ? Qt : Kt;
        const float* bias   = (c == 0) ? b0 : b1;
        const float sc      = (c == 0) ? qscale : 1.0f;
        const int obase = (o0 & 511) + wr * 64;  // 64-aligned
        const int h = obase >> 6;
        unsigned short* base = dst + (size_t)(b * 8 + h) * 65536;
        #pragma unroll
        for (int ms = 0; ms < 4; ms++) {
            int ob = obase + ms * 16 + quad * 4;
            float bv[4];
            #pragma unroll
            for (int r = 0; r < 4; r++) bv[r] = bias[ob + r];
            int d0 = ms * 16 + quad * 4;
            #pragma unroll
            for (int ns = 0; ns < 4; ns++) {
                int l = l0 + wc * 64 + ns * 16 + col;
                ushort4 hv;
                hv.x = f2bf((acc[ms][ns][0] + bv[0]) * sc);
                hv.y = f2bf((acc[ms][ns][1] + bv[1]) * sc);
                hv.z = f2bf((acc[ms][ns][2] + bv[2]) * sc);
                hv.w = f2bf((acc[ms][ns][3] + bv[3]) * sc);
                *(ushort4*)(base + (size_t)l * 64 + d0) = hv;
            }
        }
    } else {
        // ---- V epilogue: LDS transpose then coalesced rows to [bh][d][1024] ----
        __syncthreads();
        unsigned short* vt = smem;               // [128][264]
        #pragma unroll
        for (int ms = 0; ms < 4; ms++) {
            int ob = (o0 & 511) + wr * 64 + ms * 16 + quad * 4;
            #pragma unroll
            for (int ns = 0; ns < 4; ns++) {
                int lc = wc * 64 + ns * 16 + col;
                #pragma unroll
                for (int r = 0; r < 4; r++)
                    vt[(wr * 64 + ms * 16 + quad * 4 + r) * 264 + lc] =
                        f2bf(acc[ms][ns][r] + b2[ob + r]);
            }
        }
        __syncthreads();
        #pragma unroll
        for (int it = 0; it < 8; it++) {
            int flat = it * 4096 + t * 8;
            int row = flat >> 8, colx = flat & 255;
            bf16x8 v = *(const bf16x8*)&vt[row * 264 + colx];
            int og = (o0 & 511) + row;
            int h = og >> 6, d = og & 63;
            *(bf16x8*)(Vt + ((size_t)(b * 8 + h) * 64 + d) * 1024 + l0 + colx) = v;
        }
    }
}

// ---------------------------------------------------------------------------
// Flash attention, bf16 MFMA, no-max softmax (p = 2^s, log2e folded into Q).
// (unchanged from previous round)
// ---------------------------------------------------------------------------
__global__ __launch_bounds__(256, 3) void attn_kernel(
        const unsigned short* __restrict__ Qt,
        const unsigned short* __restrict__ Kt,
        const unsigned short* __restrict__ Vt,
        float* __restrict__ out) {
    __shared__ unsigned short asmem[25600];      // [2][K 4096 | V 4096] | Ps 9216
    unsigned short* Ps = asmem + 16384;          // [4 waves][32 q][72 k]

    const int t    = threadIdx.x;
    const int wave = t >> 6;
    const int lane = t & 63;
    const int col  = lane & 15;
    const int quad = lane >> 4;

    const int lin = blockIdx.y * 8 + blockIdx.x; // 0..1023
    const int xcd = lin & 7;
    const int idx = lin >> 3;                    // 0..127
    const int qb  = idx >> 4;                    // 0..7
    const int bh  = xcd * 16 + (idx & 15);       // 0..127

    const size_t base64 = (size_t)bh * 1024 * 64;
    const int q0w = qb * 128 + wave * 32;

    bf16x8 bq[2][2];
    #pragma unroll
    for (int g = 0; g < 2; g++) {
        const unsigned short* qrow = Qt + base64 + (size_t)(q0w + g * 16 + col) * 64;
        bq[g][0] = *(const bf16x8*)(qrow + quad * 8);
        bq[g][1] = *(const bf16x8*)(qrow + 32 + quad * 8);
    }

    const bf16x8 ones = (bf16x8){0x3F80, 0x3F80, 0x3F80, 0x3F80,
                                 0x3F80, 0x3F80, 0x3F80, 0x3F80};

    f32x4 o[2][4];
    #pragma unroll
    for (int g = 0; g < 2; g++)
        #pragma unroll
        for (int d = 0; d < 4; d++) o[g][d] = (f32x4){0.f, 0.f, 0.f, 0.f};
    f32x4 osum[2];
    osum[0] = (f32x4){0.f, 0.f, 0.f, 0.f};
    osum[1] = (f32x4){0.f, 0.f, 0.f, 0.f};

    const unsigned short* kg0 = Kt + base64;
    const unsigned short* vg  = Vt + base64;
    unsigned short* Pw = Ps + wave * 32 * 72;

    #pragma unroll
    for (int j = 0; j < 2; j++) {
        int i = wave + j * 4;
        int G = SWZ(i * 64 + lane);
        gl_lds16(kg0 + (size_t)G * 8, asmem + i * 512);
        int p = G >> 3, q = G & 7;
        gl_lds16(vg + (size_t)p * 1024 + q * 8, asmem + 4096 + i * 512);
    }
    asm volatile("s_waitcnt vmcnt(0)" ::: "memory");
    __builtin_amdgcn_s_barrier();
    asm volatile("" ::: "memory");

    int cur = 0;
    for (int kt = 0; kt < 16; kt++) {
        if (kt < 15) {
            const unsigned short* kg = kg0 + (size_t)(kt + 1) * 4096;
            unsigned short* Kb = asmem + (cur ^ 1) * 8192;
            #pragma unroll
            for (int j = 0; j < 2; j++) {
                int i = wave + j * 4;
                int G = SWZ(i * 64 + lane);
                gl_lds16(kg + (size_t)G * 8, Kb + i * 512);
                int p = G >> 3, q = G & 7;
                gl_lds16(vg + (size_t)p * 1024 + (kt + 1) * 64 + q * 8,
                         Kb + 4096 + i * 512);
            }
        }

        const unsigned short* Ksb = asmem + cur * 8192;
        const unsigned short* Vsb = Ksb + 4096;

        bf16x8 ak[4][2];
        #pragma unroll
        for (int sub = 0; sub < 4; sub++) {
            int rk = sub * 16 + col;
            ak[sub][0] = *(const bf16x8*)&Ksb[SWZ(rk * 8 + quad) * 8];
            ak[sub][1] = *(const bf16x8*)&Ksb[SWZ(rk * 8 + 4 + quad) * 8];
        }
        bf16x8 av[4][2];
        #pragma unroll
        for (int dsub = 0; dsub < 4; dsub++) {
            int rd = dsub * 16 + col;
            av[dsub][0] = *(const bf16x8*)&Vsb[SWZ(rd * 8 + quad) * 8];
            av[dsub][1] = *(const bf16x8*)&Vsb[SWZ(rd * 8 + 4 + quad) * 8];
        }

        #pragma unroll
        for (int g = 0; g < 2; g++) {
            #pragma unroll
            for (int sub = 0; sub < 4; sub++) {
                f32x4 a = (f32x4){0.f, 0.f, 0.f, 0.f};
                __builtin_amdgcn_s_setprio(1);
                a = __builtin_amdgcn_mfma_f32_16x16x32_bf16(ak[sub][0], bq[g][0], a, 0, 0, 0);
                a = __builtin_amdgcn_mfma_f32_16x16x32_bf16(ak[sub][1], bq[g][1], a, 0, 0, 0);
                __builtin_amdgcn_s_setprio(0);
                unsigned int u[4];
                #pragma unroll
                for (int r = 0; r < 4; r++) {
                    union { float f; unsigned int u; } c;
                    c.f = exp2f(a[r]);
                    u[r] = c.u;
                }
                if (kt == 15 && sub == 3 && quad == 3) {  // mask keys 1022,1023
                    u[2] = 0; u[3] = 0;
                }
                uint2 pk;
                pk.x = (u[0] >> 16) | (u[1] & 0xFFFF0000u);
                pk.y = (u[2] >> 16) | (u[3] & 0xFFFF0000u);
                *(uint2*)&Pw[(g * 16 + col) * 72 + sub * 16 + quad * 4] = pk;
            }
        }

        #pragma unroll
        for (int g = 0; g < 2; g++) {
            bf16x8 bp0 = *(const bf16x8*)&Pw[(g * 16 + col) * 72 + quad * 8];
            bf16x8 bp1 = *(const bf16x8*)&Pw[(g * 16 + col) * 72 + 32 + quad * 8];
            __builtin_amdgcn_s_setprio(1);
            #pragma unroll
            for (int dsub = 0; dsub < 4; dsub++) {
                o[g][dsub] = __builtin_amdgcn_mfma_f32_16x16x32_bf16(av[dsub][0], bp0, o[g][dsub], 0, 0, 0);
                o[g][dsub] = __builtin_amdgcn_mfma_f32_16x16x32_bf16(av[dsub][1], bp1, o[g][dsub], 0, 0, 0);
            }
            osum[g] = __builtin_amdgcn_mfma_f32_16x16x32_bf16(ones, bp0, osum[g], 0, 0, 0);
            osum[g] = __builtin_amdgcn_mfma_f32_16x16x32_bf16(ones, bp1, osum[g], 0, 0, 0);
            __builtin_amdgcn_s_setprio(0);
        }

        asm volatile("s_waitcnt vmcnt(0)" ::: "memory");
        __builtin_amdgcn_s_barrier();
        asm volatile("" ::: "memory");
        cur ^= 1;
    }

    #pragma unroll
    for (int g = 0; g < 2; g++) {
        int q = q0w + g * 16 + col;
        if (q < LP) {
            float inv = 1.0f / osum[g][0];
            #pragma unroll
            for (int dsub = 0; dsub < 4; dsub++) {
                #pragma unroll
                for (int r = 0; r < 4; r++) {
                    int d = dsub * 16 + quad * 4 + r;
                    out[((size_t)bh * 64 + d) * LP + q] = o[g][dsub][r] * inv;
                }
            }
        }
    }
}

// ---------------------------------------------------------------------------
extern "C" void kernel_launch(void* const* d_in, const int* in_sizes, int n_in,
                              void* d_out, int out_size, void* d_ws, size_t ws_size,
                              hipStream_t stream) {
    const float* x  = (const float*)d_in[0];
    const float* w0 = (const float*)d_in[1];
    const float* b0 = (const float*)d_in[2];
    const float* w1 = (const float*)d_in[3];
    const float* b1 = (const float*)d_in[4];
    const float* w2 = (const float*)d_in[5];
    const float* b2 = (const float*)d_in[6];
    float* out = (float*)d_out;

    // workspace (ushort units): xb 8388608 | wb 2359296 | Qt/Kt/Vt 8388608 each
    unsigned short* xbp = (unsigned short*)d_ws;
    unsigned short* wbp = xbp + 8388608;
    unsigned short* Qt  = wbp + 2359296;
    unsigned short* Kt  = Qt + 8388608;
    unsigned short* Vt  = Kt + 8388608;

    // 1/sqrt(512) * log2(e): softmax computed as 2^s
    const float scale = 0.06375870864f;

    static bool attr_done = false;
    if (!attr_done) {
        hipFuncSetAttribute((const void*)conv_mfma_kernel,
                            hipFuncAttributeMaxDynamicSharedMemorySize, 147456);
        attr_done = true;
    }

    xb_cvt_kernel<<<dim3(16, 8, 16), 256, 0, stream>>>(x, xbp);
    wb_cvt_kernel<<<dim3(3072, 3), 256, 0, stream>>>(w0, w1, w2, wbp);
    conv_mfma_kernel<<<dim3(4, 12, 16), 512, 147456, stream>>>(xbp, wbp, b0, b1, b2,
                                                               Qt, Kt, Vt, scale);
    attn_kernel<<<dim3(8, 128), 256, 0, stream>>>(Qt, Kt, Vt, out);
}

// Round 3
// 243.607 us; speedup vs baseline: 1.0406x; 1.0406x over previous
//
#include <hip/hip_runtime.h>

// Problem constants
#define B_SZ 16
#define CIN  512
#define LIN  1024
#define LP   1022      // L - K + 1
#define HEADS 8
#define DH    64

typedef __attribute__((ext_vector_type(8))) short bf16x8;
typedef __attribute__((ext_vector_type(4))) float f32x4;

__device__ inline unsigned short f2bf(float f) {
    union { float f; unsigned int u; } c; c.f = f;
    unsigned int r = c.u + 0x7FFF + ((c.u >> 16) & 1);   // RNE
    return (unsigned short)(r >> 16);
}

// async global->LDS DMA, 16B per lane, LDS dst = wave-uniform base + lane*16
__device__ __forceinline__ void gl_lds16(const unsigned short* g, unsigned short* l) {
    __builtin_amdgcn_global_load_lds((const __attribute__((address_space(1))) void*)g,
                                     (__attribute__((address_space(3))) void*)l, 16, 0, 0);
}

// XOR swizzle on 16B granules: involution, preserves 64-granule blocks,
// spreads rows across all 8 bank groups (2-way residual = free).
#define SWZ(G) ((G) ^ (((G) >> 3) & 7))

// raw barrier + compiler memory fence (LDS ops must not cross)
#define BAR() do { asm volatile("" ::: "memory"); \
                   __builtin_amdgcn_s_barrier();  \
                   asm volatile("" ::: "memory"); } while (0)

// ---------------------------------------------------------------------------
// xb cvt: x fp32 [b][512 i][1024 l] -> xb bf16 [b][1024 l][512 i]
// ---------------------------------------------------------------------------
__global__ __launch_bounds__(256) void xb_cvt_kernel(const float* __restrict__ x,
                                                     unsigned short* __restrict__ xb) {
    __shared__ float sm[64][68];
    const int t  = threadIdx.x;
    const int l0 = blockIdx.x * 64;
    const int i0 = blockIdx.y * 64;
    const int b  = blockIdx.z;
    const float* S = x + ((size_t)b * CIN + i0) * LIN;

    #pragma unroll
    for (int rr = 0; rr < 4; rr++) {
        int idx = rr * 1024 + t * 4;
        int ii = idx >> 6, lj = idx & 63;
        *(float4*)&sm[ii][lj] = *(const float4*)(S + (size_t)ii * LIN + l0 + lj);
    }
    __syncthreads();

    #pragma unroll
    for (int rr = 0; rr < 4; rr++) {
        int idx = rr * 1024 + t * 4;
        int l = idx >> 6, dj = idx & 63;
        ushort4 h;
        h.x = f2bf(sm[dj + 0][l]);
        h.y = f2bf(sm[dj + 1][l]);
        h.z = f2bf(sm[dj + 2][l]);
        h.w = f2bf(sm[dj + 3][l]);
        *(ushort4*)(xb + ((size_t)b * 1024 + l0 + l) * 512 + i0 + dj) = h;
    }
}

// ---------------------------------------------------------------------------
// wb cvt: w_c[o][i][kk] fp32 -> wb bf16 [kk][O=c*512+o][i]
// ---------------------------------------------------------------------------
__global__ __launch_bounds__(256) void wb_cvt_kernel(const float* __restrict__ w0,
                                                     const float* __restrict__ w1,
                                                     const float* __restrict__ w2,
                                                     unsigned short* __restrict__ wb) {
    const int kk = blockIdx.y;
    int flat = blockIdx.x * 256 + threadIdx.x;
    int i  = flat & 511;
    int oG = flat >> 9;
    int c  = oG >> 9, o = oG & 511;
    const float* w = (c == 0) ? w0 : (c == 1) ? w1 : w2;
    wb[(size_t)kk * 786432 + flat] = f2bf(w[o * 1536 + i * 3 + kk]);
}

// ---------------------------------------------------------------------------
// Fused 3-conv bf16 MFMA GEMM — 2-phase/K-tile counted-vmcnt (T3+T4+T5).
// BM=128(o) x BN=256(l) x BK=64, 24 K-tiles (kk folded into K: kt -> kk=kt>>3,
// ic=(kt&7)*64; kk shifts the B *global* row address, halo-free). 512 threads,
// 8 waves (2M x 4N, 64x64 per wave). Triple-buffered LDS (3 x 48KB = 144KB):
// stage kt+2 during kt's phases -> boundary vmcnt(6), never 0.
// 2 phases/K-tile, each with a 16-MFMA cluster (8 MFMA per barrier — the m201
// amortization ratio; round-1's 4-phase/8-MFMA-cluster was barrier-bound).
// Grid 4x12x16 = 768 blocks = exactly 3 rounds of 256 CUs (100% balance).
// ---------------------------------------------------------------------------
extern __shared__ unsigned short smem[];

__device__ __forceinline__ void stage_chunkA(const unsigned short* wbase,
                                             unsigned short* bufA, int wave, int lane) {
    #pragma unroll
    for (int j = 0; j < 2; j++) {
        int i = wave * 2 + j;                    // instr 0..15 (128 rows x 8 gran)
        int G = SWZ(i * 64 + lane);
        gl_lds16(wbase + (size_t)(G >> 3) * 512 + (G & 7) * 8, bufA + i * 512);
    }
}

__device__ __forceinline__ void stage_chunkB(const unsigned short* xbase,
                                             unsigned short* bufB, int half,
                                             int wave, int lane) {
    #pragma unroll
    for (int j = 0; j < 2; j++) {
        int i = half * 16 + wave * 2 + j;        // instr 0..31 (256 rows x 8 gran)
        int G = SWZ(i * 64 + lane);
        gl_lds16(xbase + (size_t)(G >> 3) * 512 + (G & 7) * 8, bufB + i * 512);
    }
}

__device__ __forceinline__ bf16x8 ldfrag(const unsigned short* buf, int row,
                                         int ks, int quad) {
    int G = (row << 3) | (ks << 2) | quad;
    return *(const bf16x8*)&buf[SWZ(G) * 8];
}

__device__ __forceinline__ void ktile(int kt,
        const unsigned short* __restrict__ wb, const unsigned short* __restrict__ xrow,
        int o0, int l0, int wave, int lane, int col, int quad, int wr, int wc,
        unsigned short* BA, unsigned short* BB,
        unsigned short* NA, unsigned short* NB, f32x4 (&acc)[4][4]) {
    const int kn  = kt + 2;
    const int kkn = kn >> 3, icn = (kn & 7) << 6;
    const int ar = wr * 64 + col;                // A-frag row base
    const int br = wc * 64 + col;                // B-frag row base

    bf16x8 A[4][2], Bf[4][2];

    // ---- phase 0: left C-half (n=0,1); stage A(kt+2) + B-half0(kt+2) ----
    #pragma unroll
    for (int m = 0; m < 4; m++) {
        A[m][0] = ldfrag(BA, ar + m * 16, 0, quad);
        A[m][1] = ldfrag(BA, ar + m * 16, 1, quad);
    }
    #pragma unroll
    for (int ks = 0; ks < 2; ks++) {
        Bf[0][ks] = ldfrag(BB, br,      ks, quad);
        Bf[1][ks] = ldfrag(BB, br + 16, ks, quad);
    }
    if (kt < 22) {
        stage_chunkA(wb + (size_t)kkn * 786432 + (size_t)o0 * 512 + icn, NA, wave, lane);
        stage_chunkB(xrow + (size_t)(l0 + kkn) * 512 + icn, NB, 0, wave, lane);
    }
    BAR();
    __builtin_amdgcn_s_setprio(1);
    #pragma unroll
    for (int ks = 0; ks < 2; ks++)
        #pragma unroll
        for (int m = 0; m < 4; m++) {
            acc[m][0] = __builtin_amdgcn_mfma_f32_16x16x32_bf16(A[m][ks], Bf[0][ks], acc[m][0], 0, 0, 0);
            acc[m][1] = __builtin_amdgcn_mfma_f32_16x16x32_bf16(A[m][ks], Bf[1][ks], acc[m][1], 0, 0, 0);
        }
    __builtin_amdgcn_s_setprio(0);
    BAR();

    // ---- phase 1: right C-half (n=2,3); stage B-half1(kt+2) ----
    #pragma unroll
    for (int ks = 0; ks < 2; ks++) {
        Bf[2][ks] = ldfrag(BB, br + 32, ks, quad);
        Bf[3][ks] = ldfrag(BB, br + 48, ks, quad);
    }
    if (kt < 22)
        stage_chunkB(xrow + (size_t)(l0 + kkn) * 512 + icn, NB, 1, wave, lane);
    BAR();
    __builtin_amdgcn_s_setprio(1);
    #pragma unroll
    for (int ks = 0; ks < 2; ks++)
        #pragma unroll
        for (int m = 0; m < 4; m++) {
            acc[m][2] = __builtin_amdgcn_mfma_f32_16x16x32_bf16(A[m][ks], Bf[2][ks], acc[m][2], 0, 0, 0);
            acc[m][3] = __builtin_amdgcn_mfma_f32_16x16x32_bf16(A[m][ks], Bf[3][ks], acc[m][3], 0, 0, 0);
        }
    __builtin_amdgcn_s_setprio(0);

    // ---- tile boundary: counted vmcnt (kt+1 landed; kt+2's 6 stay in flight) ----
    if (kt < 22)       asm volatile("s_waitcnt vmcnt(6)" ::: "memory");
    else if (kt == 22) asm volatile("s_waitcnt vmcnt(0)" ::: "memory");
    BAR();
}

__global__ __launch_bounds__(512, 2) void conv_mfma_kernel(
        const unsigned short* __restrict__ xb,   // [16][1024][512]
        const unsigned short* __restrict__ wb,   // [3][1536][512]
        const float* __restrict__ b0, const float* __restrict__ b1,
        const float* __restrict__ b2,
        unsigned short* __restrict__ Qt, unsigned short* __restrict__ Kt,
        unsigned short* __restrict__ Vt, float qscale) {
    const int t    = threadIdx.x;
    const int wave = t >> 6;
    const int lane = t & 63;
    const int col  = lane & 15;
    const int quad = lane >> 4;
    const int wr   = wave >> 2;                  // 0..1 (M)
    const int wc   = wave & 3;                   // 0..3 (N)
    const int l0   = blockIdx.x * 256;
    const int o0   = blockIdx.y * 128;
    const int b    = blockIdx.z;

    // buffers: 3 x (A 8192 | B 16384) ushorts
    unsigned short* b0A = smem;          unsigned short* b0B = smem + 8192;
    unsigned short* b1A = smem + 24576;  unsigned short* b1B = smem + 32768;
    unsigned short* b2A = smem + 49152;  unsigned short* b2B = smem + 57344;

    f32x4 acc[4][4];
    #pragma unroll
    for (int i = 0; i < 4; i++)
        #pragma unroll
        for (int j = 0; j < 4; j++) acc[i][j] = (f32x4){0.f, 0.f, 0.f, 0.f};

    const unsigned short* xrow = xb + (size_t)b * 1024 * 512;

    // ---- prologue: stage kt0 -> buf0, kt1 -> buf1 (both kk=0) ----
    stage_chunkA(wb + (size_t)o0 * 512,        b0A, wave, lane);
    stage_chunkB(xrow + (size_t)l0 * 512,      b0B, 0, wave, lane);
    stage_chunkB(xrow + (size_t)l0 * 512,      b0B, 1, wave, lane);
    stage_chunkA(wb + (size_t)o0 * 512 + 64,   b1A, wave, lane);
    stage_chunkB(xrow + (size_t)l0 * 512 + 64, b1B, 0, wave, lane);
    stage_chunkB(xrow + (size_t)l0 * 512 + 64, b1B, 1, wave, lane);
    asm volatile("s_waitcnt vmcnt(6)" ::: "memory");   // kt0 landed; kt1 in flight
    BAR();

    // ---- main loop: 24 K-tiles, buffers rotate mod 3 ----
    #pragma unroll 1
    for (int ktb = 0; ktb < 24; ktb += 3) {
        ktile(ktb,     wb, xrow, o0, l0, wave, lane, col, quad, wr, wc,
              b0A, b0B, b2A, b2B, acc);
        ktile(ktb + 1, wb, xrow, o0, l0, wave, lane, col, quad, wr, wc,
              b1A, b1B, b0A, b0B, acc);
        ktile(ktb + 2, wb, xrow, o0, l0, wave, lane, col, quad, wr, wc,
              b2A, b2B, b1A, b1B, acc);
    }

    const int c = blockIdx.y >> 2;               // which conv (uniform per block)

    if (c < 2) {
        // ---- Q/K epilogue: direct bf16 stores to [bh][l][d] ----
        unsigned short* dst = (c == 0) ? Qt : Kt;
        const float* bias   = (c == 0) ? b0 : b1;
        const float sc      = (c == 0) ? qscale : 1.0f;
        const int obase = (o0 & 511) + wr * 64;  // 64-aligned
        const int h = obase >> 6;
        unsigned short* base = dst + (size_t)(b * 8 + h) * 65536;
        #pragma unroll
        for (int ms = 0; ms < 4; ms++) {
            int ob = obase + ms * 16 + quad * 4;
            float bv[4];
            #pragma unroll
            for (int r = 0; r < 4; r++) bv[r] = bias[ob + r];
            int d0 = ms * 16 + quad * 4;
            #pragma unroll
            for (int ns = 0; ns < 4; ns++) {
                int l = l0 + wc * 64 + ns * 16 + col;
                ushort4 hv;
                hv.x = f2bf((acc[ms][ns][0] + bv[0]) * sc);
                hv.y = f2bf((acc[ms][ns][1] + bv[1]) * sc);
                hv.z = f2bf((acc[ms][ns][2] + bv[2]) * sc);
                hv.w = f2bf((acc[ms][ns][3] + bv[3]) * sc);
                *(ushort4*)(base + (size_t)l * 64 + d0) = hv;
            }
        }
    } else {
        // ---- V epilogue: LDS transpose then coalesced rows to [bh][d][1024] ----
        __syncthreads();
        unsigned short* vt = smem;               // [128][264]
        #pragma unroll
        for (int ms = 0; ms < 4; ms++) {
            int ob = (o0 & 511) + wr * 64 + ms * 16 + quad * 4;
            #pragma unroll
            for (int ns = 0; ns < 4; ns++) {
                int lc = wc * 64 + ns * 16 + col;
                #pragma unroll
                for (int r = 0; r < 4; r++)
                    vt[(wr * 64 + ms * 16 + quad * 4 + r) * 264 + lc] =
                        f2bf(acc[ms][ns][r] + b2[ob + r]);
            }
        }
        __syncthreads();
        #pragma unroll
        for (int it = 0; it < 8; it++) {
            int flat = it * 4096 + t * 8;
            int row = flat >> 8, colx = flat & 255;
            bf16x8 v = *(const bf16x8*)&vt[row * 264 + colx];
            int og = (o0 & 511) + row;
            int h = og >> 6, d = og & 63;
            *(bf16x8*)(Vt + ((size_t)(b * 8 + h) * 64 + d) * 1024 + l0 + colx) = v;
        }
    }
}

// ---------------------------------------------------------------------------
// Flash attention, bf16 MFMA, no-max softmax (p = 2^s, log2e folded into Q).
// (unchanged)
// ---------------------------------------------------------------------------
__global__ __launch_bounds__(256, 3) void attn_kernel(
        const unsigned short* __restrict__ Qt,
        const unsigned short* __restrict__ Kt,
        const unsigned short* __restrict__ Vt,
        float* __restrict__ out) {
    __shared__ unsigned short asmem[25600];      // [2][K 4096 | V 4096] | Ps 9216
    unsigned short* Ps = asmem + 16384;          // [4 waves][32 q][72 k]

    const int t    = threadIdx.x;
    const int wave = t >> 6;
    const int lane = t & 63;
    const int col  = lane & 15;
    const int quad = lane >> 4;

    const int lin = blockIdx.y * 8 + blockIdx.x; // 0..1023
    const int xcd = lin & 7;
    const int idx = lin >> 3;                    // 0..127
    const int qb  = idx >> 4;                    // 0..7
    const int bh  = xcd * 16 + (idx & 15);       // 0..127

    const size_t base64 = (size_t)bh * 1024 * 64;
    const int q0w = qb * 128 + wave * 32;

    bf16x8 bq[2][2];
    #pragma unroll
    for (int g = 0; g < 2; g++) {
        const unsigned short* qrow = Qt + base64 + (size_t)(q0w + g * 16 + col) * 64;
        bq[g][0] = *(const bf16x8*)(qrow + quad * 8);
        bq[g][1] = *(const bf16x8*)(qrow + 32 + quad * 8);
    }

    const bf16x8 ones = (bf16x8){0x3F80, 0x3F80, 0x3F80, 0x3F80,
                                 0x3F80, 0x3F80, 0x3F80, 0x3F80};

    f32x4 o[2][4];
    #pragma unroll
    for (int g = 0; g < 2; g++)
        #pragma unroll
        for (int d = 0; d < 4; d++) o[g][d] = (f32x4){0.f, 0.f, 0.f, 0.f};
    f32x4 osum[2];
    osum[0] = (f32x4){0.f, 0.f, 0.f, 0.f};
    osum[1] = (f32x4){0.f, 0.f, 0.f, 0.f};

    const unsigned short* kg0 = Kt + base64;
    const unsigned short* vg  = Vt + base64;
    unsigned short* Pw = Ps + wave * 32 * 72;

    #pragma unroll
    for (int j = 0; j < 2; j++) {
        int i = wave + j * 4;
        int G = SWZ(i * 64 + lane);
        gl_lds16(kg0 + (size_t)G * 8, asmem + i * 512);
        int p = G >> 3, q = G & 7;
        gl_lds16(vg + (size_t)p * 1024 + q * 8, asmem + 4096 + i * 512);
    }
    asm volatile("s_waitcnt vmcnt(0)" ::: "memory");
    __builtin_amdgcn_s_barrier();
    asm volatile("" ::: "memory");

    int cur = 0;
    for (int kt = 0; kt < 16; kt++) {
        if (kt < 15) {
            const unsigned short* kg = kg0 + (size_t)(kt + 1) * 4096;
            unsigned short* Kb = asmem + (cur ^ 1) * 8192;
            #pragma unroll
            for (int j = 0; j < 2; j++) {
                int i = wave + j * 4;
                int G = SWZ(i * 64 + lane);
                gl_lds16(kg + (size_t)G * 8, Kb + i * 512);
                int p = G >> 3, q = G & 7;
                gl_lds16(vg + (size_t)p * 1024 + (kt + 1) * 64 + q * 8,
                         Kb + 4096 + i * 512);
            }
        }

        const unsigned short* Ksb = asmem + cur * 8192;
        const unsigned short* Vsb = Ksb + 4096;

        bf16x8 ak[4][2];
        #pragma unroll
        for (int sub = 0; sub < 4; sub++) {
            int rk = sub * 16 + col;
            ak[sub][0] = *(const bf16x8*)&Ksb[SWZ(rk * 8 + quad) * 8];
            ak[sub][1] = *(const bf16x8*)&Ksb[SWZ(rk * 8 + 4 + quad) * 8];
        }
        bf16x8 av[4][2];
        #pragma unroll
        for (int dsub = 0; dsub < 4; dsub++) {
            int rd = dsub * 16 + col;
            av[dsub][0] = *(const bf16x8*)&Vsb[SWZ(rd * 8 + quad) * 8];
            av[dsub][1] = *(const bf16x8*)&Vsb[SWZ(rd * 8 + 4 + quad) * 8];
        }

        #pragma unroll
        for (int g = 0; g < 2; g++) {
            #pragma unroll
            for (int sub = 0; sub < 4; sub++) {
                f32x4 a = (f32x4){0.f, 0.f, 0.f, 0.f};
                __builtin_amdgcn_s_setprio(1);
                a = __builtin_amdgcn_mfma_f32_16x16x32_bf16(ak[sub][0], bq[g][0], a, 0, 0, 0);
                a = __builtin_amdgcn_mfma_f32_16x16x32_bf16(ak[sub][1], bq[g][1], a, 0, 0, 0);
                __builtin_amdgcn_s_setprio(0);
                unsigned int u[4];
                #pragma unroll
                for (int r = 0; r < 4; r++) {
                    union { float f; unsigned int u; } c;
                    c.f = exp2f(a[r]);
                    u[r] = c.u;
                }
                if (kt == 15 && sub == 3 && quad == 3) {  // mask keys 1022,1023
                    u[2] = 0; u[3] = 0;
                }
                uint2 pk;
                pk.x = (u[0] >> 16) | (u[1] & 0xFFFF0000u);
                pk.y = (u[2] >> 16) | (u[3] & 0xFFFF0000u);
                *(uint2*)&Pw[(g * 16 + col) * 72 + sub * 16 + quad * 4] = pk;
            }
        }

        #pragma unroll
        for (int g = 0; g < 2; g++) {
            bf16x8 bp0 = *(const bf16x8*)&Pw[(g * 16 + col) * 72 + quad * 8];
            bf16x8 bp1 = *(const bf16x8*)&Pw[(g * 16 + col) * 72 + 32 + quad * 8];
            __builtin_amdgcn_s_setprio(1);
            #pragma unroll
            for (int dsub = 0; dsub < 4; dsub++) {
                o[g][dsub] = __builtin_amdgcn_mfma_f32_16x16x32_bf16(av[dsub][0], bp0, o[g][dsub], 0, 0, 0);
                o[g][dsub] = __builtin_amdgcn_mfma_f32_16x16x32_bf16(av[dsub][1], bp1, o[g][dsub], 0, 0, 0);
            }
            osum[g] = __builtin_amdgcn_mfma_f32_16x16x32_bf16(ones, bp0, osum[g], 0, 0, 0);
            osum[g] = __builtin_amdgcn_mfma_f32_16x16x32_bf16(ones, bp1, osum[g], 0, 0, 0);
            __builtin_amdgcn_s_setprio(0);
        }

        asm volatile("s_waitcnt vmcnt(0)" ::: "memory");
        __builtin_amdgcn_s_barrier();
        asm volatile("" ::: "memory");
        cur ^= 1;
    }

    #pragma unroll
    for (int g = 0; g < 2; g++) {
        int q = q0w + g * 16 + col;
        if (q < LP) {
            float inv = 1.0f / osum[g][0];
            #pragma unroll
            for (int dsub = 0; dsub < 4; dsub++) {
                #pragma unroll
                for (int r = 0; r < 4; r++) {
                    int d = dsub * 16 + quad * 4 + r;
                    out[((size_t)bh * 64 + d) * LP + q] = o[g][dsub][r] * inv;
                }
            }
        }
    }
}

// ---------------------------------------------------------------------------
extern "C" void kernel_launch(void* const* d_in, const int* in_sizes, int n_in,
                              void* d_out, int out_size, void* d_ws, size_t ws_size,
                              hipStream_t stream) {
    const float* x  = (const float*)d_in[0];
    const float* w0 = (const float*)d_in[1];
    const float* b0 = (const float*)d_in[2];
    const float* w1 = (const float*)d_in[3];
    const float* b1 = (const float*)d_in[4];
    const float* w2 = (const float*)d_in[5];
    const float* b2 = (const float*)d_in[6];
    float* out = (float*)d_out;

    // workspace (ushort units): xb 8388608 | wb 2359296 | Qt/Kt/Vt 8388608 each
    unsigned short* xbp = (unsigned short*)d_ws;
    unsigned short* wbp = xbp + 8388608;
    unsigned short* Qt  = wbp + 2359296;
    unsigned short* Kt  = Qt + 8388608;
    unsigned short* Vt  = Kt + 8388608;

    // 1/sqrt(512) * log2(e): softmax computed as 2^s
    const float scale = 0.06375870864f;

    static bool attr_done = false;
    if (!attr_done) {
        hipFuncSetAttribute((const void*)conv_mfma_kernel,
                            hipFuncAttributeMaxDynamicSharedMemorySize, 147456);
        attr_done = true;
    }

    xb_cvt_kernel<<<dim3(16, 8, 16), 256, 0, stream>>>(x, xbp);
    wb_cvt_kernel<<<dim3(3072, 3), 256, 0, stream>>>(w0, w1, w2, wbp);
    conv_mfma_kernel<<<dim3(4, 12, 16), 512, 147456, stream>>>(xbp, wbp, b0, b1, b2,
                                                               Qt, Kt, Vt, scale);
    attn_kernel<<<dim3(8, 128), 256, 0, stream>>>(Qt, Kt, Vt, out);
}

// Round 5
// 239.445 us; speedup vs baseline: 1.0587x; 1.0174x over previous
//
#include <hip/hip_runtime.h>

// Problem constants
#define B_SZ 16
#define CIN  512
#define LIN  1024
#define LP   1022      // L - K + 1
#define HEADS 8
#define DH    64

typedef __attribute__((ext_vector_type(8))) short bf16x8;
typedef __attribute__((ext_vector_type(4))) float f32x4;

__device__ inline unsigned short f2bf(float f) {
    union { float f; unsigned int u; } c; c.f = f;
    unsigned int r = c.u + 0x7FFF + ((c.u >> 16) & 1);   // RNE
    return (unsigned short)(r >> 16);
}

// async global->LDS DMA, 16B per lane, LDS dst = wave-uniform base + lane*16
__device__ __forceinline__ void gl_lds16(const unsigned short* g, unsigned short* l) {
    __builtin_amdgcn_global_load_lds((const __attribute__((address_space(1))) void*)g,
                                     (__attribute__((address_space(3))) void*)l, 16, 0, 0);
}

// XOR swizzle on 16B granules: involution, preserves 8-granule blocks,
// spreads 16 consecutive rows across all 8 bank groups (2-way = free).
#define SWZ(G) ((G) ^ (((G) >> 3) & 7))

// ---------------------------------------------------------------------------
// xb cvt: x fp32 [b][512 i][1024 l] -> xb bf16 [b][1024 l][512 i]
// ---------------------------------------------------------------------------
__global__ __launch_bounds__(256) void xb_cvt_kernel(const float* __restrict__ x,
                                                     unsigned short* __restrict__ xb) {
    __shared__ float sm[64][68];
    const int t  = threadIdx.x;
    const int l0 = blockIdx.x * 64;
    const int i0 = blockIdx.y * 64;
    const int b  = blockIdx.z;
    const float* S = x + ((size_t)b * CIN + i0) * LIN;

    #pragma unroll
    for (int rr = 0; rr < 4; rr++) {
        int idx = rr * 1024 + t * 4;
        int ii = idx >> 6, lj = idx & 63;
        *(float4*)&sm[ii][lj] = *(const float4*)(S + (size_t)ii * LIN + l0 + lj);
    }
    __syncthreads();

    #pragma unroll
    for (int rr = 0; rr < 4; rr++) {
        int idx = rr * 1024 + t * 4;
        int l = idx >> 6, dj = idx & 63;
        ushort4 h;
        h.x = f2bf(sm[dj + 0][l]);
        h.y = f2bf(sm[dj + 1][l]);
        h.z = f2bf(sm[dj + 2][l]);
        h.w = f2bf(sm[dj + 3][l]);
        *(ushort4*)(xb + ((size_t)b * 1024 + l0 + l) * 512 + i0 + dj) = h;
    }
}

// ---------------------------------------------------------------------------
// wb cvt: w_c[o][i][kk] fp32 -> wb bf16 [kk][O=c*512+o][i]
// ---------------------------------------------------------------------------
__global__ __launch_bounds__(256) void wb_cvt_kernel(const float* __restrict__ w0,
                                                     const float* __restrict__ w1,
                                                     const float* __restrict__ w2,
                                                     unsigned short* __restrict__ wb) {
    const int kk = blockIdx.y;
    int flat = blockIdx.x * 256 + threadIdx.x;
    int i  = flat & 511;
    int oG = flat >> 9;
    int c  = oG >> 9, o = oG & 511;
    const float* w = (c == 0) ? w0 : (c == 1) ? w1 : w2;
    wb[(size_t)kk * 786432 + flat] = f2bf(w[o * 1536 + i * 3 + kk]);
}

// ---------------------------------------------------------------------------
// Fused 3-conv bf16 MFMA GEMM with global_load_lds staging + XOR-swizzled LDS.
// Round-0 structure (93 us, the m97 plateau): two 8-phase ports (round 1/2)
// both regressed — at 64x64/wave the phase clusters are too short to
// amortize the added barriers.
// ---------------------------------------------------------------------------
__global__ __launch_bounds__(256) void conv_mfma_kernel(
        const unsigned short* __restrict__ xb,   // [16][1024][512]
        const unsigned short* __restrict__ wb,   // [3][1536][512]
        const float* __restrict__ b0, const float* __restrict__ b1,
        const float* __restrict__ b2,
        unsigned short* __restrict__ Qt, unsigned short* __restrict__ Kt,
        unsigned short* __restrict__ Vt, float qscale) {
    __shared__ unsigned short smem[16896];       // staging 16512 sh | vt 16896 sh
    unsigned short* xs = smem;                   // [132][32]
    unsigned short* ws = smem + 4224;            // [384][32]

    const int t    = threadIdx.x;
    const int wave = t >> 6;
    const int lane = t & 63;
    const int col  = lane & 15;
    const int quad = lane >> 4;
    const int wh   = wave >> 1;                  // o half
    const int wn   = wave & 1;                   // l half
    const int l0   = blockIdx.x * 128;
    const int o0   = blockIdx.y * 128;
    const int b    = blockIdx.z;

    f32x4 acc[4][4];
    #pragma unroll
    for (int i = 0; i < 4; i++)
        #pragma unroll
        for (int j = 0; j < 4; j++) acc[i][j] = (f32x4){0.f, 0.f, 0.f, 0.f};

    const unsigned short* xrow = xb + (size_t)b * 1024 * 512;

    for (int ic = 0; ic < 512; ic += 32) {
        __syncthreads();   // previous chunk's compute done before overwrite

        // ---- W DMA: 24 instrs (16 rows each), this wave does 6 ----
        #pragma unroll
        for (int j = 0; j < 6; j++) {
            int instr = wave * 6 + j;
            int Gg = SWZ(instr * 64 + lane);
            int p = Gg >> 2, q = Gg & 3;
            int kk = p >> 7, orow = p & 127;
            gl_lds16(wb + ((size_t)(kk * 1536 + o0 + orow)) * 512 + ic + q * 8,
                     ws + instr * 512);
        }
        // ---- X DMA: 8 instrs for rows 0..127, this wave does 2 ----
        #pragma unroll
        for (int j = 0; j < 2; j++) {
            int instr = wave * 2 + j;
            int Gg = SWZ(instr * 64 + lane);
            int p = Gg >> 2, q = Gg & 3;
            gl_lds16(xrow + (size_t)(l0 + p) * 512 + ic + q * 8,
                     xs + instr * 512);
        }
        // ---- halo rows 128,129 (checked, zero-fill OOB) ----
        if (t < 8) {
            int row = 128 + (t >> 2), sg = t & 3;
            int gl = l0 + row;
            bf16x8 v = (bf16x8){0, 0, 0, 0, 0, 0, 0, 0};
            if (gl < 1024) v = *(const bf16x8*)(xrow + (size_t)gl * 512 + ic + sg * 8);
            *(bf16x8*)&xs[SWZ(512 + t) * 8] = v;
        }
        __syncthreads();   // drains vmcnt (DMA) + lgkmcnt (halo)

        #pragma unroll
        for (int kk = 0; kk < 3; kk++) {
            bf16x8 af[4], bfr[4];
            #pragma unroll
            for (int ms = 0; ms < 4; ms++) {
                int G = ((kk * 128 + wh * 64 + ms * 16 + col) << 2) | quad;
                af[ms] = *(const bf16x8*)&ws[SWZ(G) * 8];
            }
            #pragma unroll
            for (int ns = 0; ns < 4; ns++) {
                int G = ((wn * 64 + ns * 16 + col + kk) << 2) | quad;
                bfr[ns] = *(const bf16x8*)&xs[SWZ(G) * 8];
            }
            #pragma unroll
            for (int ms = 0; ms < 4; ms++)
                #pragma unroll
                for (int ns = 0; ns < 4; ns++)
                    acc[ms][ns] = __builtin_amdgcn_mfma_f32_16x16x32_bf16(af[ms], bfr[ns], acc[ms][ns], 0, 0, 0);
        }
    }

    const int c = blockIdx.y >> 2;               // which conv (uniform per block)

    if (c < 2) {
        // ---- Q/K epilogue: direct bf16 stores to [bh][l][d] ----
        unsigned short* dst = (c == 0) ? Qt : Kt;
        const float* bias   = (c == 0) ? b0 : b1;
        const float sc      = (c == 0) ? qscale : 1.0f;
        const int h = (((o0 & 511) + wh * 64) >> 6) & 7;
        unsigned short* base = dst + (size_t)(b * 8 + h) * 65536;
        #pragma unroll
        for (int ms = 0; ms < 4; ms++) {
            int ob = (o0 & 511) + wh * 64 + ms * 16 + quad * 4;
            float bv[4];
            #pragma unroll
            for (int r = 0; r < 4; r++) bv[r] = bias[ob + r];
            int d0 = ms * 16 + quad * 4;
            #pragma unroll
            for (int ns = 0; ns < 4; ns++) {
                int l = l0 + wn * 64 + ns * 16 + col;
                ushort4 hv;
                hv.x = f2bf((acc[ms][ns][0] + bv[0]) * sc);
                hv.y = f2bf((acc[ms][ns][1] + bv[1]) * sc);
                hv.z = f2bf((acc[ms][ns][2] + bv[2]) * sc);
                hv.w = f2bf((acc[ms][ns][3] + bv[3]) * sc);
                *(ushort4*)(base + (size_t)l * 64 + d0) = hv;
            }
        }
    } else {
        // ---- V epilogue: LDS transpose then coalesced rows to [bh][d][1024] ----
        __syncthreads();
        unsigned short* vt = smem;               // [128][132]
        #pragma unroll
        for (int ms = 0; ms < 4; ms++) {
            int ob = (o0 & 511) + wh * 64 + ms * 16 + quad * 4;
            #pragma unroll
            for (int ns = 0; ns < 4; ns++) {
                int lc = wn * 64 + ns * 16 + col;
                #pragma unroll
                for (int r = 0; r < 4; r++)
                    vt[(wh * 64 + ms * 16 + quad * 4 + r) * 132 + lc] =
                        f2bf(acc[ms][ns][r] + b2[ob + r]);
            }
        }
        __syncthreads();
        #pragma unroll
        for (int it = 0; it < 8; it++) {
            int flat = it * 2048 + t * 8;
            int row = flat >> 7, colx = flat & 127;
            bf16x8 v = *(const bf16x8*)&vt[row * 132 + colx];
            int og = (o0 & 511) + row;
            int h = og >> 6, d = og & 63;
            *(bf16x8*)(Vt + ((size_t)(b * 8 + h) * 64 + d) * 1024 + l0 + colx) = v;
        }
    }
}

// ---------------------------------------------------------------------------
// Flash attention, bf16 MFMA, no-max softmax (p = 2^s, log2e folded into Q).
// S^T formulation: A=K, B=Q -> P exits with 4 contiguous k per lane
// (packed ds_write_b64), reads back as B-operand for PV (A=V).
//
// 64 q per wave (4 q-groups) — K/V LDS frag reads and K/V DMA are shared
// across 2x the work (the dominant LDS pipe per unit work halves);
// v_cvt_pk_bf16_f32 packing (2 instr per 4 P-values vs 6 bit-ops).
// Grid (4,128) = 512 blocks = 2 exact CU rounds. LDS 68KB -> 2 blocks/CU.
// ---------------------------------------------------------------------------
__global__ __launch_bounds__(256, 2) void attn_kernel(
        const unsigned short* __restrict__ Qt,
        const unsigned short* __restrict__ Kt,
        const unsigned short* __restrict__ Vt,
        float* __restrict__ out) {
    __shared__ unsigned short asmem[34816];      // [2][K 4096 | V 4096] | Ps 18432
    unsigned short* Ps = asmem + 16384;          // [4 waves][64 q][72 k]

    const int t    = threadIdx.x;
    const int wave = t >> 6;
    const int lane = t & 63;
    const int col  = lane & 15;
    const int quad = lane >> 4;

    // XCD-grouping swizzle (bijective over the 512-block grid): each XCD gets
    // 16 bh x 4 qb, so K/V panels are reused within one L2.
    const int lin = blockIdx.y * 4 + blockIdx.x; // 0..511
    const int xcd = lin & 7;
    const int idx = lin >> 3;                    // 0..63
    const int qb  = idx >> 4;                    // 0..3
    const int bh  = xcd * 16 + (idx & 15);       // 0..127

    const size_t base64 = (size_t)bh * 1024 * 64;
    const int q0w = qb * 256 + wave * 64;

    // Q as B-operand frags: bq[g][h], rows q0w + g*16 + col
    bf16x8 bq[4][2];
    #pragma unroll
    for (int g = 0; g < 4; g++) {
        const unsigned short* qrow = Qt + base64 + (size_t)(q0w + g * 16 + col) * 64;
        bq[g][0] = *(const bf16x8*)(qrow + quad * 8);
        bq[g][1] = *(const bf16x8*)(qrow + 32 + quad * 8);
    }

    const bf16x8 ones = (bf16x8){0x3F80, 0x3F80, 0x3F80, 0x3F80,
                                 0x3F80, 0x3F80, 0x3F80, 0x3F80};

    f32x4 o[4][4];                               // [q-group][d-subtile]
    #pragma unroll
    for (int g = 0; g < 4; g++)
        #pragma unroll
        for (int d = 0; d < 4; d++) o[g][d] = (f32x4){0.f, 0.f, 0.f, 0.f};
    f32x4 osum[4];
    #pragma unroll
    for (int g = 0; g < 4; g++) osum[g] = (f32x4){0.f, 0.f, 0.f, 0.f};

    const unsigned short* kg0 = Kt + base64;
    const unsigned short* vg  = Vt + base64;
    unsigned short* Pw = Ps + wave * 64 * 72;

    // ---- prologue: stage tile 0 -> buf0 ----
    #pragma unroll
    for (int j = 0; j < 2; j++) {
        int i = wave + j * 4;                    // instr 0..7
        int G = SWZ(i * 64 + lane);
        gl_lds16(kg0 + (size_t)G * 8, asmem + i * 512);
        int p = G >> 3, q = G & 7;
        gl_lds16(vg + (size_t)p * 1024 + q * 8, asmem + 4096 + i * 512);
    }
    asm volatile("s_waitcnt vmcnt(0)" ::: "memory");
    __builtin_amdgcn_s_barrier();
    asm volatile("" ::: "memory");

    int cur = 0;
    for (int kt = 0; kt < 16; kt++) {
        // ---- issue next tile's DMA first: latency hides under this compute ----
        if (kt < 15) {
            const unsigned short* kg = kg0 + (size_t)(kt + 1) * 4096;
            unsigned short* Kb = asmem + (cur ^ 1) * 8192;
            #pragma unroll
            for (int j = 0; j < 2; j++) {
                int i = wave + j * 4;
                int G = SWZ(i * 64 + lane);
                gl_lds16(kg + (size_t)G * 8, Kb + i * 512);
                int p = G >> 3, q = G & 7;
                gl_lds16(vg + (size_t)p * 1024 + (kt + 1) * 64 + q * 8,
                         Kb + 4096 + i * 512);
            }
        }

        const unsigned short* Ksb = asmem + cur * 8192;
        const unsigned short* Vsb = Ksb + 4096;

        // ---- K A-frags (shared across all 4 q-groups) ----
        bf16x8 ak[4][2];
        #pragma unroll
        for (int sub = 0; sub < 4; sub++) {
            int rk = sub * 16 + col;
            ak[sub][0] = *(const bf16x8*)&Ksb[SWZ(rk * 8 + quad) * 8];
            ak[sub][1] = *(const bf16x8*)&Ksb[SWZ(rk * 8 + 4 + quad) * 8];
        }

        // ---- S^T = K Q^T ; p = 2^s ; cvt_pk + packed transpose store ----
        #pragma unroll
        for (int g = 0; g < 4; g++) {
            #pragma unroll
            for (int sub = 0; sub < 4; sub++) {
                f32x4 a = (f32x4){0.f, 0.f, 0.f, 0.f};
                __builtin_amdgcn_s_setprio(1);
                a = __builtin_amdgcn_mfma_f32_16x16x32_bf16(ak[sub][0], bq[g][0], a, 0, 0, 0);
                a = __builtin_amdgcn_mfma_f32_16x16x32_bf16(ak[sub][1], bq[g][1], a, 0, 0, 0);
                __builtin_amdgcn_s_setprio(0);
                // p = exp2(s); lane rows are k = sub*16 + quad*4 + r
                float e0 = exp2f(a[0]), e1 = exp2f(a[1]);
                float e2 = exp2f(a[2]), e3 = exp2f(a[3]);
                uint2 pk;
                asm("v_cvt_pk_bf16_f32 %0, %1, %2" : "=v"(pk.x) : "v"(e0), "v"(e1));
                asm("v_cvt_pk_bf16_f32 %0, %1, %2" : "=v"(pk.y) : "v"(e2), "v"(e3));
                if (kt == 15 && sub == 3 && quad == 3)   // mask keys 1022,1023
                    pk.y = 0;
                *(uint2*)&Pw[(g * 16 + col) * 72 + sub * 16 + quad * 4] = pk;
            }
        }

        // ---- V A-frags ----
        bf16x8 av[4][2];
        #pragma unroll
        for (int dsub = 0; dsub < 4; dsub++) {
            int rd = dsub * 16 + col;
            av[dsub][0] = *(const bf16x8*)&Vsb[SWZ(rd * 8 + quad) * 8];
            av[dsub][1] = *(const bf16x8*)&Vsb[SWZ(rd * 8 + 4 + quad) * 8];
        }

        // ---- O += V P ; rowsums via ones-MFMA ----
        #pragma unroll
        for (int g = 0; g < 4; g++) {
            bf16x8 bp0 = *(const bf16x8*)&Pw[(g * 16 + col) * 72 + quad * 8];
            bf16x8 bp1 = *(const bf16x8*)&Pw[(g * 16 + col) * 72 + 32 + quad * 8];
            __builtin_amdgcn_s_setprio(1);
            #pragma unroll
            for (int dsub = 0; dsub < 4; dsub++) {
                o[g][dsub] = __builtin_amdgcn_mfma_f32_16x16x32_bf16(av[dsub][0], bp0, o[g][dsub], 0, 0, 0);
                o[g][dsub] = __builtin_amdgcn_mfma_f32_16x16x32_bf16(av[dsub][1], bp1, o[g][dsub], 0, 0, 0);
            }
            osum[g] = __builtin_amdgcn_mfma_f32_16x16x32_bf16(ones, bp0, osum[g], 0, 0, 0);
            osum[g] = __builtin_amdgcn_mfma_f32_16x16x32_bf16(ones, bp1, osum[g], 0, 0, 0);
            __builtin_amdgcn_s_setprio(0);
        }

        // ---- single barrier per tile: prefetch landed + all reads retired ----
        asm volatile("s_waitcnt vmcnt(0)" ::: "memory");
        __builtin_amdgcn_s_barrier();
        asm volatile("" ::: "memory");
        cur ^= 1;
    }

    // ---- epilogue: out[bh*64 + d][q] = o / rowsum ----
    // D layout: col = n = q (within group), rows m = d = dsub*16 + quad*4 + r
    #pragma unroll
    for (int g = 0; g < 4; g++) {
        int q = q0w + g * 16 + col;
        if (q < LP) {
            float inv = 1.0f / osum[g][0];       // all rows identical
            #pragma unroll
            for (int dsub = 0; dsub < 4; dsub++) {
                #pragma unroll
                for (int r = 0; r < 4; r++) {
                    int d = dsub * 16 + quad * 4 + r;
                    out[((size_t)bh * 64 + d) * LP + q] = o[g][dsub][r] * inv;
                }
            }
        }
    }
}

// ---------------------------------------------------------------------------
extern "C" void kernel_launch(void* const* d_in, const int* in_sizes, int n_in,
                              void* d_out, int out_size, void* d_ws, size_t ws_size,
                              hipStream_t stream) {
    const float* x  = (const float*)d_in[0];
    const float* w0 = (const float*)d_in[1];
    const float* b0 = (const float*)d_in[2];
    const float* w1 = (const float*)d_in[3];
    const float* b1 = (const float*)d_in[4];
    const float* w2 = (const float*)d_in[5];
    const float* b2 = (const float*)d_in[6];
    float* out = (float*)d_out;

    // workspace (ushort units): xb 8388608 | wb 2359296 | Qt/Kt/Vt 8388608 each
    unsigned short* xbp = (unsigned short*)d_ws;
    unsigned short* wbp = xbp + 8388608;
    unsigned short* Qt  = wbp + 2359296;
    unsigned short* Kt  = Qt + 8388608;
    unsigned short* Vt  = Kt + 8388608;

    // 1/sqrt(512) * log2(e): softmax computed as 2^s
    const float scale = 0.06375870864f;

    xb_cvt_kernel<<<dim3(16, 8, 16), 256, 0, stream>>>(x, xbp);
    wb_cvt_kernel<<<dim3(3072, 3), 256, 0, stream>>>(w0, w1, w2, wbp);
    conv_mfma_kernel<<<dim3(8, 12, 16), 256, 0, stream>>>(xbp, wbp, b0, b1, b2,
                                                          Qt, Kt, Vt, scale);
    attn_kernel<<<dim3(4, 128), 256, 0, stream>>>(Qt, Kt, Vt, out);
}

// Round 6
// 233.409 us; speedup vs baseline: 1.0860x; 1.0259x over previous
//
#include <hip/hip_runtime.h>

// Problem constants
#define B_SZ 16
#define CIN  512
#define LIN  1024
#define LP   1022      // L - K + 1
#define HEADS 8
#define DH    64

typedef __attribute__((ext_vector_type(8))) short bf16x8;
typedef __attribute__((ext_vector_type(4))) float f32x4;
typedef __attribute__((ext_vector_type(16))) float f32x16;

__device__ inline unsigned short f2bf(float f) {
    union { float f; unsigned int u; } c; c.f = f;
    unsigned int r = c.u + 0x7FFF + ((c.u >> 16) & 1);   // RNE
    return (unsigned short)(r >> 16);
}

// async global->LDS DMA, 16B per lane, LDS dst = wave-uniform base + lane*16
__device__ __forceinline__ void gl_lds16(const unsigned short* g, unsigned short* l) {
    __builtin_amdgcn_global_load_lds((const __attribute__((address_space(1))) void*)g,
                                     (__attribute__((address_space(3))) void*)l, 16, 0, 0);
}

// XOR swizzle on 16B granules: involution, preserves 8-granule blocks,
// spreads 16 consecutive rows across all 8 bank groups (2-way = free).
#define SWZ(G) ((G) ^ (((G) >> 3) & 7))

// ---------------------------------------------------------------------------
// xb cvt: x fp32 [b][512 i][1024 l] -> xb bf16 [b][1024 l][512 i]
// ---------------------------------------------------------------------------
__global__ __launch_bounds__(256) void xb_cvt_kernel(const float* __restrict__ x,
                                                     unsigned short* __restrict__ xb) {
    __shared__ float sm[64][68];
    const int t  = threadIdx.x;
    const int l0 = blockIdx.x * 64;
    const int i0 = blockIdx.y * 64;
    const int b  = blockIdx.z;
    const float* S = x + ((size_t)b * CIN + i0) * LIN;

    #pragma unroll
    for (int rr = 0; rr < 4; rr++) {
        int idx = rr * 1024 + t * 4;
        int ii = idx >> 6, lj = idx & 63;
        *(float4*)&sm[ii][lj] = *(const float4*)(S + (size_t)ii * LIN + l0 + lj);
    }
    __syncthreads();

    #pragma unroll
    for (int rr = 0; rr < 4; rr++) {
        int idx = rr * 1024 + t * 4;
        int l = idx >> 6, dj = idx & 63;
        ushort4 h;
        h.x = f2bf(sm[dj + 0][l]);
        h.y = f2bf(sm[dj + 1][l]);
        h.z = f2bf(sm[dj + 2][l]);
        h.w = f2bf(sm[dj + 3][l]);
        *(ushort4*)(xb + ((size_t)b * 1024 + l0 + l) * 512 + i0 + dj) = h;
    }
}

// ---------------------------------------------------------------------------
// wb cvt: w_c[o][i][kk] fp32 -> wb bf16 [kk][O=c*512+o][i]
// ---------------------------------------------------------------------------
__global__ __launch_bounds__(256) void wb_cvt_kernel(const float* __restrict__ w0,
                                                     const float* __restrict__ w1,
                                                     const float* __restrict__ w2,
                                                     unsigned short* __restrict__ wb) {
    const int kk = blockIdx.y;
    int flat = blockIdx.x * 256 + threadIdx.x;
    int i  = flat & 511;
    int oG = flat >> 9;
    int c  = oG >> 9, o = oG & 511;
    const float* w = (c == 0) ? w0 : (c == 1) ? w1 : w2;
    wb[(size_t)kk * 786432 + flat] = f2bf(w[o * 1536 + i * 3 + kk]);
}

// ---------------------------------------------------------------------------
// Fused 3-conv bf16 MFMA GEMM with global_load_lds staging + XOR-swizzled LDS.
// Round-0 structure (93 us, the m97 plateau; 8-phase ports regressed).
// ---------------------------------------------------------------------------
__global__ __launch_bounds__(256) void conv_mfma_kernel(
        const unsigned short* __restrict__ xb,   // [16][1024][512]
        const unsigned short* __restrict__ wb,   // [3][1536][512]
        const float* __restrict__ b0, const float* __restrict__ b1,
        const float* __restrict__ b2,
        unsigned short* __restrict__ Qt, unsigned short* __restrict__ Kt,
        unsigned short* __restrict__ Vt, float qscale) {
    __shared__ unsigned short smem[16896];       // staging 16512 sh | vt 16896 sh
    unsigned short* xs = smem;                   // [132][32]
    unsigned short* ws = smem + 4224;            // [384][32]

    const int t    = threadIdx.x;
    const int wave = t >> 6;
    const int lane = t & 63;
    const int col  = lane & 15;
    const int quad = lane >> 4;
    const int wh   = wave >> 1;                  // o half
    const int wn   = wave & 1;                   // l half
    const int l0   = blockIdx.x * 128;
    const int o0   = blockIdx.y * 128;
    const int b    = blockIdx.z;

    f32x4 acc[4][4];
    #pragma unroll
    for (int i = 0; i < 4; i++)
        #pragma unroll
        for (int j = 0; j < 4; j++) acc[i][j] = (f32x4){0.f, 0.f, 0.f, 0.f};

    const unsigned short* xrow = xb + (size_t)b * 1024 * 512;

    for (int ic = 0; ic < 512; ic += 32) {
        __syncthreads();   // previous chunk's compute done before overwrite

        // ---- W DMA: 24 instrs (16 rows each), this wave does 6 ----
        #pragma unroll
        for (int j = 0; j < 6; j++) {
            int instr = wave * 6 + j;
            int Gg = SWZ(instr * 64 + lane);
            int p = Gg >> 2, q = Gg & 3;
            int kk = p >> 7, orow = p & 127;
            gl_lds16(wb + ((size_t)(kk * 1536 + o0 + orow)) * 512 + ic + q * 8,
                     ws + instr * 512);
        }
        // ---- X DMA: 8 instrs for rows 0..127, this wave does 2 ----
        #pragma unroll
        for (int j = 0; j < 2; j++) {
            int instr = wave * 2 + j;
            int Gg = SWZ(instr * 64 + lane);
            int p = Gg >> 2, q = Gg & 3;
            gl_lds16(xrow + (size_t)(l0 + p) * 512 + ic + q * 8,
                     xs + instr * 512);
        }
        // ---- halo rows 128,129 (checked, zero-fill OOB) ----
        if (t < 8) {
            int row = 128 + (t >> 2), sg = t & 3;
            int gl = l0 + row;
            bf16x8 v = (bf16x8){0, 0, 0, 0, 0, 0, 0, 0};
            if (gl < 1024) v = *(const bf16x8*)(xrow + (size_t)gl * 512 + ic + sg * 8);
            *(bf16x8*)&xs[SWZ(512 + t) * 8] = v;
        }
        __syncthreads();   // drains vmcnt (DMA) + lgkmcnt (halo)

        #pragma unroll
        for (int kk = 0; kk < 3; kk++) {
            bf16x8 af[4], bfr[4];
            #pragma unroll
            for (int ms = 0; ms < 4; ms++) {
                int G = ((kk * 128 + wh * 64 + ms * 16 + col) << 2) | quad;
                af[ms] = *(const bf16x8*)&ws[SWZ(G) * 8];
            }
            #pragma unroll
            for (int ns = 0; ns < 4; ns++) {
                int G = ((wn * 64 + ns * 16 + col + kk) << 2) | quad;
                bfr[ns] = *(const bf16x8*)&xs[SWZ(G) * 8];
            }
            #pragma unroll
            for (int ms = 0; ms < 4; ms++)
                #pragma unroll
                for (int ns = 0; ns < 4; ns++)
                    acc[ms][ns] = __builtin_amdgcn_mfma_f32_16x16x32_bf16(af[ms], bfr[ns], acc[ms][ns], 0, 0, 0);
        }
    }

    const int c = blockIdx.y >> 2;               // which conv (uniform per block)

    if (c < 2) {
        // ---- Q/K epilogue: direct bf16 stores to [bh][l][d] ----
        unsigned short* dst = (c == 0) ? Qt : Kt;
        const float* bias   = (c == 0) ? b0 : b1;
        const float sc      = (c == 0) ? qscale : 1.0f;
        const int h = (((o0 & 511) + wh * 64) >> 6) & 7;
        unsigned short* base = dst + (size_t)(b * 8 + h) * 65536;
        #pragma unroll
        for (int ms = 0; ms < 4; ms++) {
            int ob = (o0 & 511) + wh * 64 + ms * 16 + quad * 4;
            float bv[4];
            #pragma unroll
            for (int r = 0; r < 4; r++) bv[r] = bias[ob + r];
            int d0 = ms * 16 + quad * 4;
            #pragma unroll
            for (int ns = 0; ns < 4; ns++) {
                int l = l0 + wn * 64 + ns * 16 + col;
                ushort4 hv;
                hv.x = f2bf((acc[ms][ns][0] + bv[0]) * sc);
                hv.y = f2bf((acc[ms][ns][1] + bv[1]) * sc);
                hv.z = f2bf((acc[ms][ns][2] + bv[2]) * sc);
                hv.w = f2bf((acc[ms][ns][3] + bv[3]) * sc);
                *(ushort4*)(base + (size_t)l * 64 + d0) = hv;
            }
        }
    } else {
        // ---- V epilogue: LDS transpose then coalesced rows to [bh][d][1024] ----
        __syncthreads();
        unsigned short* vt = smem;               // [128][132]
        #pragma unroll
        for (int ms = 0; ms < 4; ms++) {
            int ob = (o0 & 511) + wh * 64 + ms * 16 + quad * 4;
            #pragma unroll
            for (int ns = 0; ns < 4; ns++) {
                int lc = wn * 64 + ns * 16 + col;
                #pragma unroll
                for (int r = 0; r < 4; r++)
                    vt[(wh * 64 + ms * 16 + quad * 4 + r) * 132 + lc] =
                        f2bf(acc[ms][ns][r] + b2[ob + r]);
            }
        }
        __syncthreads();
        #pragma unroll
        for (int it = 0; it < 8; it++) {
            int flat = it * 2048 + t * 8;
            int row = flat >> 7, colx = flat & 127;
            bf16x8 v = *(const bf16x8*)&vt[row * 132 + colx];
            int og = (o0 & 511) + row;
            int h = og >> 6, d = og & 63;
            *(bf16x8*)(Vt + ((size_t)(b * 8 + h) * 64 + d) * 1024 + l0 + colx) = v;
        }
    }
}

// ---------------------------------------------------------------------------
// Flash attention, 32x32x16 MFMA, no-max softmax (p = 2^s, log2e in Q).
// Swapped QK (A=K, B=Q): lane (col5=q, hi) holds S^T k-subset in 16 f32 regs.
// P never touches LDS: exp + rowsum in-register; B-frag for PV built with
// cvt_pk_bf16 + shfl_xor(32) cross-half exchange (T12 pattern).
// Per wave per k-tile: 16 MFMA (8 QK + 8 PV, zero waste), 16 ds_read_b128,
// 0 ds_write. LDS = K/V dbuf only (32KB) -> 3 blocks/CU, desynced.
// 4 waves x 32 q = 128 q/block; grid (8 qb, 128 bh) = 1024 blocks.
// ---------------------------------------------------------------------------
__global__ __launch_bounds__(256, 3) void attn_kernel(
        const unsigned short* __restrict__ Qt,
        const unsigned short* __restrict__ Kt,
        const unsigned short* __restrict__ Vt,
        float* __restrict__ out) {
    __shared__ unsigned short asmem[16384];      // [2][K 4096 | V 4096]

    const int t    = threadIdx.x;
    const int wave = t >> 6;
    const int lane = t & 63;
    const int col5 = lane & 31;
    const int hi   = lane >> 5;

    // XCD-grouping swizzle (bijective over the 1024-block grid): each XCD
    // gets 16 bh x 8 qb, so K/V panels are reused within one L2.
    const int lin = blockIdx.y * 8 + blockIdx.x; // 0..1023
    const int xcd = lin & 7;
    const int idx = lin >> 3;                    // 0..127
    const int qb  = idx >> 4;                    // 0..7
    const int bh  = xcd * 16 + (idx & 15);       // 0..127

    const size_t base64 = (size_t)bh * 65536;
    const int q0 = qb * 128 + wave * 32;

    // Q B-frags: bq[s] = Q[q0+col5][s*16 + hi*8 + e]
    bf16x8 bq[4];
    {
        const unsigned short* qrow = Qt + base64 + (size_t)(q0 + col5) * 64 + hi * 8;
        #pragma unroll
        for (int s = 0; s < 4; s++) bq[s] = *(const bf16x8*)(qrow + s * 16);
    }

    f32x16 o0, o1;                               // O[d=col-rows], d-blocks 0/1
    #pragma unroll
    for (int i = 0; i < 16; i++) { o0[i] = 0.f; o1[i] = 0.f; }
    float osum = 0.f;

    const unsigned short* kg0 = Kt + base64;
    const unsigned short* vg  = Vt + base64;

    // ---- prologue: stage tile 0 -> buf0 ----
    #pragma unroll
    for (int j = 0; j < 2; j++) {
        int i = wave + j * 4;                    // instr 0..7
        int G = SWZ(i * 64 + lane);
        gl_lds16(kg0 + (size_t)G * 8, asmem + i * 512);
        int p = G >> 3, q = G & 7;
        gl_lds16(vg + (size_t)p * 1024 + q * 8, asmem + 4096 + i * 512);
    }
    asm volatile("s_waitcnt vmcnt(0)" ::: "memory");
    __builtin_amdgcn_s_barrier();
    asm volatile("" ::: "memory");

    int cur = 0;
    for (int kt = 0; kt < 16; kt++) {
        // ---- issue next tile's DMA first: latency hides under compute ----
        if (kt < 15) {
            const unsigned short* kg = kg0 + (size_t)(kt + 1) * 4096;
            unsigned short* Kb = asmem + (cur ^ 1) * 8192;
            #pragma unroll
            for (int j = 0; j < 2; j++) {
                int i = wave + j * 4;
                int G = SWZ(i * 64 + lane);
                gl_lds16(kg + (size_t)G * 8, Kb + i * 512);
                int p = G >> 3, q = G & 7;
                gl_lds16(vg + (size_t)p * 1024 + (kt + 1) * 64 + q * 8,
                         Kb + 4096 + i * 512);
            }
        }

        const unsigned short* Ksb = asmem + cur * 8192;
        const unsigned short* Vsb = Ksb + 4096;

        #pragma unroll
        for (int kb = 0; kb < 2; kb++) {
            // ---- frag reads: K rows kb*32+col5, V rows db*32+col5 ----
            bf16x8 ak[4];
            #pragma unroll
            for (int s = 0; s < 4; s++)
                ak[s] = *(const bf16x8*)&Ksb[SWZ((kb * 32 + col5) * 8 + s * 2 + hi) * 8];
            bf16x8 av[2][2];
            #pragma unroll
            for (int db = 0; db < 2; db++)
                #pragma unroll
                for (int s = 0; s < 2; s++)
                    av[db][s] = *(const bf16x8*)&Vsb[SWZ((db * 32 + col5) * 8 + kb * 4 + s * 2 + hi) * 8];

            // ---- S^T = K Q^T over d (4 chained K=16 steps) ----
            f32x16 p;
            #pragma unroll
            for (int i = 0; i < 16; i++) p[i] = 0.f;
            __builtin_amdgcn_s_setprio(1);
            #pragma unroll
            for (int s = 0; s < 4; s++)
                p = __builtin_amdgcn_mfma_f32_32x32x16_bf16(ak[s], bq[s], p, 0, 0, 0);
            __builtin_amdgcn_s_setprio(0);

            // ---- p = 2^s in-register; rowsum locally ----
            float e[16];
            #pragma unroll
            for (int r = 0; r < 16; r++) e[r] = exp2f(p[r]);
            if (kt == 15 && kb == 1 && hi == 1) { e[14] = 0.f; e[15] = 0.f; }  // keys 1022,1023
            #pragma unroll
            for (int r = 0; r < 16; r++) osum += e[r];

            // ---- build PV B-frags: cvt_pk + cross-half exchange ----
            bf16x8 bp[2];
            #pragma unroll
            for (int s = 0; s < 2; s++) {
                unsigned int a, b_, c, d;
                asm("v_cvt_pk_bf16_f32 %0, %1, %2" : "=v"(a)  : "v"(e[s*8+0]), "v"(e[s*8+1]));
                asm("v_cvt_pk_bf16_f32 %0, %1, %2" : "=v"(b_) : "v"(e[s*8+2]), "v"(e[s*8+3]));
                asm("v_cvt_pk_bf16_f32 %0, %1, %2" : "=v"(c)  : "v"(e[s*8+4]), "v"(e[s*8+5]));
                asm("v_cvt_pk_bf16_f32 %0, %1, %2" : "=v"(d)  : "v"(e[s*8+6]), "v"(e[s*8+7]));
                unsigned int as = (unsigned int)__shfl_xor((int)a,  32);
                unsigned int bs = (unsigned int)__shfl_xor((int)b_, 32);
                unsigned int cs = (unsigned int)__shfl_xor((int)c,  32);
                unsigned int ds = (unsigned int)__shfl_xor((int)d,  32);
                union { unsigned int u[4]; bf16x8 v; } pk;
                pk.u[0] = hi ? cs : a;           // B word0: k(0,1)/(8,9)
                pk.u[1] = hi ? ds : b_;          // B word1: k(2,3)/(10,11)
                pk.u[2] = hi ? c  : as;          // B word2: k(4,5)/(12,13)
                pk.u[3] = hi ? d  : bs;          // B word3: k(6,7)/(14,15)
                bp[s] = pk.v;
            }

            // ---- O += V P ----
            __builtin_amdgcn_s_setprio(1);
            #pragma unroll
            for (int s = 0; s < 2; s++) {
                o0 = __builtin_amdgcn_mfma_f32_32x32x16_bf16(av[0][s], bp[s], o0, 0, 0, 0);
                o1 = __builtin_amdgcn_mfma_f32_32x32x16_bf16(av[1][s], bp[s], o1, 0, 0, 0);
            }
            __builtin_amdgcn_s_setprio(0);
        }

        // ---- single barrier per tile: prefetch landed + reads retired ----
        asm volatile("s_waitcnt vmcnt(0)" ::: "memory");
        __builtin_amdgcn_s_barrier();
        asm volatile("" ::: "memory");
        cur ^= 1;
    }

    // ---- epilogue: rowsum cross-half combine, divide, store ----
    float osum_t = osum + __shfl_xor(osum, 32);
    float inv = 1.0f / osum_t;
    int q = q0 + col5;
    if (q < LP) {
        #pragma unroll
        for (int r = 0; r < 16; r++) {
            int d0 = (r & 3) + 8 * (r >> 2) + 4 * hi;
            out[((size_t)(bh * 64 + d0)) * LP + q]      = o0[r] * inv;
            out[((size_t)(bh * 64 + d0 + 32)) * LP + q] = o1[r] * inv;
        }
    }
}

// ---------------------------------------------------------------------------
extern "C" void kernel_launch(void* const* d_in, const int* in_sizes, int n_in,
                              void* d_out, int out_size, void* d_ws, size_t ws_size,
                              hipStream_t stream) {
    const float* x  = (const float*)d_in[0];
    const float* w0 = (const float*)d_in[1];
    const float* b0 = (const float*)d_in[2];
    const float* w1 = (const float*)d_in[3];
    const float* b1 = (const float*)d_in[4];
    const float* w2 = (const float*)d_in[5];
    const float* b2 = (const float*)d_in[6];
    float* out = (float*)d_out;

    // workspace (ushort units): xb 8388608 | wb 2359296 | Qt/Kt/Vt 8388608 each
    unsigned short* xbp = (unsigned short*)d_ws;
    unsigned short* wbp = xbp + 8388608;
    unsigned short* Qt  = wbp + 2359296;
    unsigned short* Kt  = Qt + 8388608;
    unsigned short* Vt  = Kt + 8388608;

    // 1/sqrt(512) * log2(e): softmax computed as 2^s
    const float scale = 0.06375870864f;

    xb_cvt_kernel<<<dim3(16, 8, 16), 256, 0, stream>>>(x, xbp);
    wb_cvt_kernel<<<dim3(3072, 3), 256, 0, stream>>>(w0, w1, w2, wbp);
    conv_mfma_kernel<<<dim3(8, 12, 16), 256, 0, stream>>>(xbp, wbp, b0, b1, b2,
                                                          Qt, Kt, Vt, scale);
    attn_kernel<<<dim3(8, 128), 256, 0, stream>>>(Qt, Kt, Vt, out);
}